// Round 7
// baseline (451.976 us; speedup 1.0000x reference)
//
#include <hip/hip_runtime.h>

// InductionNetwork capsule routing, C=256, K=64, H=1024, 3 iterations.
// R14: R13 (single persistent kernel, hand-rolled grid barriers) was
// functionally correct but ran at VGPR_Count=64: __launch_bounds__(1024,4)
// only sets a MIN waves/EU, and the compiler targeted 8 waves/EU ->
// 64-VGPR budget -> the pinned er[4][4] consumed the entire file and all
// working state spilled to scratch (374us, VALUBusy 1.9%). R14 single
// change: __attribute__((amdgpu_waves_per_eu(4,4))) pins occupancy to
// exactly 4 waves/EU -> 128-VGPR budget, no spills, and (VGPR>64) exactly
// 1 block/CU so the 256 blocks place evenly and barriers don't straggle.
// Phases (7 barriers):
//   P0 conv W -> Wt split-bf16 (transposed)       [all 256 blocks]
//   P1 Q = Wt Wt^T (64x64 tile/block) ; routing0 -> s
//   P2 y = Q s (blocks 0..127) ; W -> Wb into Wx (blocks 128..255)
//   P3 routing1: norm=s.y -> scale; b = scale*(E.y); s
//   P4 y = Q s
//   P5 routing2: b += scale*(E.y); s
//   P6 chat = W s (B = Wb)
//   P7 squash -> out
// Split-bf16 operands (verified R6-R13, absmax 4.88e-4):
//   D = Ah.Bh + Ah.Bl + Al.Bh with hi=bf16(x), lo=bf16(x-hi).
// Fragment layout verified R4/R6/R7: A[m=lane&15][k=(lane>>4)*8+j];
// C/D col=lane&15, row=(lane>>4)*4+reg.
// Fallback: R3's proven monolithic kernel if ws too small.

using f32x4  = __attribute__((ext_vector_type(4))) float;
using f32x2  = __attribute__((ext_vector_type(2))) float;
using bf16x8 = __attribute__((ext_vector_type(8))) __bf16;
using bf16x4 = __attribute__((ext_vector_type(4))) __bf16;

#define NBLK 256u

struct BfPair { __bf16 hi, lo; };
__device__ inline BfPair split_bf16(float x) {
    BfPair p;
    p.hi = (__bf16)x;
    p.lo = (__bf16)(x - (float)p.hi);
    return p;
}

// ---------------- LDS shapes ------------------------------------------------
struct RoutSM {
    float spart[16][1024];  // 64 KB: per-wave partial s
    float u_s[1024];        //  4 KB: y staged for the dots
    float b_s[64], d_s[64], red_s[16], scale_s;
};
struct QSmem {
    __bf16 a_hi[64 * 64];
    __bf16 a_lo[64 * 64];
    __bf16 b_hi[64 * 64];
    __bf16 b_lo[64 * 64];
};
union SM {
    RoutSM r;               // 68.6 KB
    QSmem q;                // 32 KB
    float tile[64][65];     // 16.6 KB (conv transpose staging)
};

// ---------------- grid barrier (sense-reversing, device scope) --------------
// All 256 blocks are co-resident by construction (1 block/CU at >64 VGPR),
// so spinning is deadlock-free. __threadfence() release-side flushes this
// XCD's L2; acquire-side invalidates so cross-XCD stores are seen.
__device__ __forceinline__ void gbar(unsigned* cnt, unsigned* gen)
{
    __syncthreads();
    if (threadIdx.x == 0) {
        __threadfence();    // release: make my block's stores visible
        const unsigned g =
            __hip_atomic_load(gen, __ATOMIC_RELAXED, __HIP_MEMORY_SCOPE_AGENT);
        const unsigned a =
            __hip_atomic_fetch_add(cnt, 1u, __ATOMIC_ACQ_REL,
                                   __HIP_MEMORY_SCOPE_AGENT);
        if (a == NBLK - 1u) {
            __hip_atomic_store(cnt, 0u, __ATOMIC_RELAXED,
                               __HIP_MEMORY_SCOPE_AGENT);
            __hip_atomic_fetch_add(gen, 1u, __ATOMIC_RELEASE,
                                   __HIP_MEMORY_SCOPE_AGENT);
        } else {
            while (__hip_atomic_load(gen, __ATOMIC_ACQUIRE,
                                     __HIP_MEMORY_SCOPE_AGENT) == g)
                __builtin_amdgcn_s_sleep(8);
        }
        __threadfence();    // acquire: drop stale lines before next phase
    }
    __syncthreads();
}

// ---------------- routing body (verified R11/R12, unchanged) ----------------
// Block = capsule c, 16 waves. Wave w owns enc rows w*4..w*4+3; lane holds
// 16 floats/row (64 VGPRs, pinned). MODE 0: d uniform. MODE 1: b =
// scale*(E.y). MODE 2: b += scale*(E.y).
template <int MODE>
__device__ __forceinline__ void routing_body(
    int c, const float* __restrict__ enc, const float* __restrict__ y0,
    const float* __restrict__ y1, float* __restrict__ bglob,
    __bf16* __restrict__ s_hi, __bf16* __restrict__ s_lo, RoutSM* sm)
{
    const int t = threadIdx.x, lane = t & 63, w = t >> 6;   // 16 waves
    const float* E = enc + (size_t)c * 65536;

    float yv = 0.f, sv = 0.f;
    if (MODE > 0) {
        const size_t o = (size_t)c * 1024 + t;
        yv = y0[o] + y1[o];                       // y = Q s (full K)
        sv = (float)s_hi[o] + (float)s_lo[o];     // s as the gemm saw it
    }

    f32x4 er[4][4];                     // 64 VGPRs of enc
    #pragma unroll
    for (int r = 0; r < 4; ++r) {
        const float* ek = E + (size_t)(w * 4 + r) * 1024 + lane * 8;
        er[r][0] = *(const f32x4*)(ek);
        er[r][1] = *(const f32x4*)(ek + 4);
        er[r][2] = *(const f32x4*)(ek + 512);
        er[r][3] = *(const f32x4*)(ek + 516);
    }
    // Pin er in VGPRs (R10 post-mortem: without this the compiler
    // rematerializes the enc tile instead of keeping it resident).
    #pragma unroll
    for (int r = 0; r < 4; ++r)
        #pragma unroll
        for (int q = 0; q < 4; ++q)
            asm volatile("" : "+v"(er[r][q]));

    if (MODE > 0) {
        sm->u_s[t] = yv;
        float p = yv * sv;                        // norm = s^T Q s = |W s|^2
        #pragma unroll
        for (int off = 32; off; off >>= 1) p += __shfl_xor(p, off, 64);
        if (lane == 0) sm->red_s[w] = p;
        __syncthreads();
        if (t == 0) {
            float n = 0.f;
            #pragma unroll
            for (int i = 0; i < 16; ++i) n += sm->red_s[i];
            sm->scale_s = n / ((1.f + n) * sqrtf(n) + 1e-30f);
        }
        __syncthreads();
        const float scale = sm->scale_s;
        f32x4 uf[4];
        uf[0] = *(const f32x4*)&sm->u_s[lane * 8];
        uf[1] = *(const f32x4*)&sm->u_s[lane * 8 + 4];
        uf[2] = *(const f32x4*)&sm->u_s[512 + lane * 8];
        uf[3] = *(const f32x4*)&sm->u_s[512 + lane * 8 + 4];
        #pragma unroll
        for (int r = 0; r < 4; ++r) {
            float sum = 0.f;
            #pragma unroll
            for (int q = 0; q < 4; ++q)
                #pragma unroll
                for (int j = 0; j < 4; ++j)
                    sum += er[r][q][j] * uf[q][j];
            #pragma unroll
            for (int off = 32; off; off >>= 1) sum += __shfl_xor(sum, off, 64);
            if (lane == 0) {
                const int k = w * 4 + r;
                const float bv =
                    (MODE == 2 ? bglob[c * 64 + k] : 0.f) + scale * sum;
                bglob[c * 64 + k] = bv;     // persist for next iteration
                sm->b_s[k] = bv;
            }
        }
    }
    __syncthreads();

    if (MODE == 0) {
        if (t < 64) sm->d_s[t] = 1.f / 64.f;
    } else if (t < 64) {
        float bv = sm->b_s[t], m = bv;
        #pragma unroll
        for (int off = 32; off; off >>= 1) m = fmaxf(m, __shfl_xor(m, off, 64));
        const float e = expf(bv - m);
        float smm = e;
        #pragma unroll
        for (int off = 32; off; off >>= 1) smm += __shfl_xor(smm, off, 64);
        sm->d_s[t] = e / smm;
    }
    __syncthreads();

    // per-wave partial s from registers (4 rows each)
    #pragma unroll
    for (int q = 0; q < 4; ++q) {
        f32x4 p = {};
        #pragma unroll
        for (int r = 0; r < 4; ++r) {
            const float dk = sm->d_s[w * 4 + r];
            #pragma unroll
            for (int j = 0; j < 4; ++j) p[j] += dk * er[r][q][j];
        }
        const int h = (q >> 1) * 512 + lane * 8 + (q & 1) * 4;
        *(f32x4*)&sm->spart[w][h] = p;
    }
    __syncthreads();

    // cross-wave reduce: 1 h-element per thread; emit split-bf16 s
    {
        float a = 0.f;
        #pragma unroll
        for (int wv = 0; wv < 16; ++wv) a += sm->spart[wv][t];
        const BfPair p = split_bf16(a);
        s_hi[(size_t)c * 1024 + t] = p.hi;
        s_lo[(size_t)c * 1024 + t] = p.lo;
    }
}

// ---------------- 16-wave 64x64 split-bf16 NT GEMM tile ---------------------
// 16 waves in a 4x4 grid, one 16x16 frag each; BK=64 LDS staging,
// XOR-swizzled 128-B rows. Threads [0,512) stage A rows, [512,1024) stage
// B rows. WQ=1: write split-bf16 (Q); WQ=0: write float C.
__device__ __forceinline__ int swz128(int row, int colbyte) {
    return row * 128 + (colbyte ^ ((row & 7) << 4));
}

template <int WQ>
__device__ __forceinline__ void gemm64_16w(
    const __bf16* __restrict__ Ah, const __bf16* __restrict__ Al,
    const __bf16* __restrict__ Bh, const __bf16* __restrict__ Bl,
    int arow0, int brow0, int kbeg, int kend,
    float* __restrict__ Cc, __bf16* __restrict__ Qh, __bf16* __restrict__ Ql,
    int crow0, int ccol0, QSmem* sm)
{
    const int t = threadIdx.x, lane = t & 63, w = t >> 6;
    const int wr = w >> 2, wc = w & 3;          // 4x4 wave grid
    const int half = t >> 9;                    // 0: stage A, 1: stage B
    const int sr   = (t & 511) >> 3;            // row 0..63
    const int scb  = (t & 7) * 16;              // col byte 0..112
    const __bf16* sh = half ? Bh : Ah;
    const __bf16* sl = half ? Bl : Al;
    const size_t g = (size_t)((half ? brow0 : arow0) + sr) * 1024 + scb / 2;
    char* const p_hi = (char*)(half ? sm->b_hi : sm->a_hi) + swz128(sr, scb);
    char* const p_lo = (char*)(half ? sm->b_lo : sm->a_lo) + swz128(sr, scb);

    f32x4 acc = {};
    for (int k0 = kbeg; k0 < kend; k0 += 64) {
        __syncthreads();                        // prev LDS use done
        *(bf16x8*)p_hi = *(const bf16x8*)(sh + g + k0);
        *(bf16x8*)p_lo = *(const bf16x8*)(sl + g + k0);
        __syncthreads();
        #pragma unroll
        for (int kk = 0; kk < 2; ++kk) {
            const int cb = kk * 64 + (lane >> 4) * 16;
            const int m = wr * 16 + (lane & 15);
            const int n = wc * 16 + (lane & 15);
            const bf16x8 ah = *(const bf16x8*)((char*)sm->a_hi + swz128(m, cb));
            const bf16x8 al = *(const bf16x8*)((char*)sm->a_lo + swz128(m, cb));
            const bf16x8 bh = *(const bf16x8*)((char*)sm->b_hi + swz128(n, cb));
            const bf16x8 bl = *(const bf16x8*)((char*)sm->b_lo + swz128(n, cb));
            acc = __builtin_amdgcn_mfma_f32_16x16x32_bf16(ah, bh, acc, 0, 0, 0);
            acc = __builtin_amdgcn_mfma_f32_16x16x32_bf16(ah, bl, acc, 0, 0, 0);
            acc = __builtin_amdgcn_mfma_f32_16x16x32_bf16(al, bh, acc, 0, 0, 0);
        }
    }
    const int rr = (lane >> 4) * 4, colb = lane & 15;
    #pragma unroll
    for (int r = 0; r < 4; ++r) {
        const size_t idx = (size_t)(crow0 + wr * 16 + rr + r) * 1024 +
                           ccol0 + wc * 16 + colb;
        if (WQ) {
            const BfPair p = split_bf16(acc[r]);
            Qh[idx] = p.hi;
            Ql[idx] = p.lo;
        } else {
            Cc[idx] = acc[r];
        }
    }
}

// ---------------- THE fused kernel ------------------------------------------
__global__ __launch_bounds__(1024)
__attribute__((amdgpu_waves_per_eu(4, 4)))       // R14: pin 4 waves/EU ->
void fused_kernel(                               // 128-VGPR budget, 1 blk/CU
    const float* __restrict__ enc, const float* __restrict__ W,
    float* __restrict__ outp, float* __restrict__ bglob,
    __bf16* __restrict__ s_hi, __bf16* __restrict__ s_lo,
    float* __restrict__ y0, float* __restrict__ y1,
    __bf16* __restrict__ Wx_hi, __bf16* __restrict__ Wx_lo,
    __bf16* __restrict__ Q_hi, __bf16* __restrict__ Q_lo,
    unsigned* __restrict__ bar)
{
    __shared__ union SM sm;
    const int b = blockIdx.x, t = threadIdx.x;
    unsigned* cnt = bar;
    unsigned* gen = bar + 32;   // separate cache line

    // ---- P0: W -> Wt split-bf16 (transposed) into Wx ----
    {
        const int by = b >> 4, bx4 = b & 15;
        const int tx = t & 63, tg = t >> 6;
        for (int i = tg; i < 64; i += 16)
            sm.tile[i][tx] =
                W[(size_t)(by * 64 + i) * 1024 + bx4 * 64 + tx];
        __syncthreads();
        for (int i = tg; i < 64; i += 16) {
            const size_t idx = (size_t)(bx4 * 64 + i) * 1024 + by * 64 + tx;
            const BfPair p = split_bf16(sm.tile[tx][i]);
            Wx_hi[idx] = p.hi;
            Wx_lo[idx] = p.lo;
        }
    }
    gbar(cnt, gen);

    // ---- P1: Q = Wt Wt^T (one 64x64 tile per block), then routing0 ----
    {
        const int ti = b >> 4, tj = b & 15;
        gemm64_16w<1>(Wx_hi, Wx_lo, Wx_hi, Wx_lo, ti * 64, tj * 64, 0, 1024,
                      nullptr, Q_hi, Q_lo, ti * 64, tj * 64, &sm.q);
        __syncthreads();
        routing_body<0>(b, enc, y0, y1, bglob, s_hi, s_lo, &sm.r);
    }
    gbar(cnt, gen);

    // ---- P2: y = Q s (blocks 0..127) ; W -> Wb into Wx (blocks 128..255) --
    if (b < 128) {
        const int kh = b & 1, tk = b >> 1;
        const int mt = tk >> 4, nt = tk & 15;
        gemm64_16w<0>(s_hi, s_lo, Q_hi, Q_lo, mt * 64, nt * 64,
                      kh * 512, kh * 512 + 512, kh ? y1 : y0,
                      nullptr, nullptr, mt * 64, nt * 64, &sm.q);
    } else {
        const int bb = b - 128;                 // 0..127: 8 W-rows each
        #pragma unroll
        for (int q = 0; q < 8; ++q) {
            const size_t idx = (size_t)bb * 8192 + (size_t)q * 1024 + t;
            const BfPair p = split_bf16(W[idx]);
            Wx_hi[idx] = p.hi;                  // Wt dead after P1
            Wx_lo[idx] = p.lo;
        }
    }
    gbar(cnt, gen);

    // ---- P3: routing1 ----
    routing_body<1>(b, enc, y0, y1, bglob, s_hi, s_lo, &sm.r);
    gbar(cnt, gen);

    // ---- P4: y = Q s ----
    if (b < 128) {
        const int kh = b & 1, tk = b >> 1;
        const int mt = tk >> 4, nt = tk & 15;
        gemm64_16w<0>(s_hi, s_lo, Q_hi, Q_lo, mt * 64, nt * 64,
                      kh * 512, kh * 512 + 512, kh ? y1 : y0,
                      nullptr, nullptr, mt * 64, nt * 64, &sm.q);
    }
    gbar(cnt, gen);

    // ---- P5: routing2 ----
    routing_body<2>(b, enc, y0, y1, bglob, s_hi, s_lo, &sm.r);
    gbar(cnt, gen);

    // ---- P6: chat = W s (B = Wb in Wx) ----
    if (b < 128) {
        const int kh = b & 1, tk = b >> 1;
        const int mt = tk >> 4, nt = tk & 15;
        gemm64_16w<0>(s_hi, s_lo, Wx_hi, Wx_lo, mt * 64, nt * 64,
                      kh * 512, kh * 512 + 512, kh ? y1 : y0,
                      nullptr, nullptr, mt * 64, nt * 64, &sm.q);
    }
    gbar(cnt, gen);

    // ---- P7: squash -> out ----
    {
        const int lane = t & 63, w = t >> 6;
        const size_t o = (size_t)b * 1024 + t;
        const float v = y0[o] + y1[o];
        float ss = v * v;
        #pragma unroll
        for (int off = 32; off; off >>= 1) ss += __shfl_xor(ss, off, 64);
        if (lane == 0) sm.r.red_s[w] = ss;
        __syncthreads();
        float norm = 0.f;
        #pragma unroll
        for (int i = 0; i < 16; ++i) norm += sm.r.red_s[i];
        const float scale = norm / ((1.f + norm) * sqrtf(norm) + 1e-30f);
        outp[o] = v * scale;
    }
}

// ---------------- fallback: R3's proven monolithic fp32 kernel --------------
__global__ __launch_bounds__(512) void fallback_kernel(
    const float* __restrict__ enc, const float* __restrict__ W,
    float* __restrict__ outp)
{
    __shared__ float u_s[1024], s_s[1024], c_s[1024], chat_s[1024];
    __shared__ float b_s[64], d_s[64], red_s[8];
    const int t = threadIdx.x, lane = t & 63, w = t >> 6;
    const float* erow = enc + (size_t)blockIdx.x * 65536;

    if (t < 64) b_s[t] = 0.f;
    __syncthreads();

    for (int it = 0; it < 3; ++it) {
        if (it > 0) {
            f32x4 uf[4];
            #pragma unroll
            for (int q = 0; q < 2; ++q) {
                uf[2*q]   = *(const f32x4*)&u_s[q*512 + lane*8];
                uf[2*q+1] = *(const f32x4*)&u_s[q*512 + lane*8 + 4];
            }
            for (int r = 0; r < 8; ++r) {
                const int k = w * 8 + r;
                const float* ek = erow + (size_t)k * 1024;
                float sum = 0.f;
                #pragma unroll
                for (int q = 0; q < 2; ++q) {
                    f32x4 e0 = *(const f32x4*)(ek + q*512 + lane*8);
                    f32x4 e1 = *(const f32x4*)(ek + q*512 + lane*8 + 4);
                    #pragma unroll
                    for (int j = 0; j < 4; ++j) {
                        sum += e0[j] * uf[2*q][j];
                        sum += e1[j] * uf[2*q+1][j];
                    }
                }
                #pragma unroll
                for (int off = 32; off; off >>= 1) sum += __shfl_xor(sum, off, 64);
                if (lane == 0) b_s[k] += sum;
            }
            __syncthreads();
        }
        if (t < 64) {
            float bv = b_s[t], m = bv;
            #pragma unroll
            for (int off = 32; off; off >>= 1) m = fmaxf(m, __shfl_xor(m, off, 64));
            float e = expf(bv - m), sm = e;
            #pragma unroll
            for (int off = 32; off; off >>= 1) sm += __shfl_xor(sm, off, 64);
            d_s[t] = e / sm;
        }
        __syncthreads();
        {
            const int h0 = t * 2;
            float a0 = 0.f, a1 = 0.f;
            for (int k = 0; k < 64; ++k) {
                f32x2 ev = *(const f32x2*)(erow + (size_t)k * 1024 + h0);
                a0 += d_s[k] * ev[0]; a1 += d_s[k] * ev[1];
            }
            s_s[h0] = a0; s_s[h0+1] = a1;
        }
        __syncthreads();
        {
            f32x4 sf[4];
            #pragma unroll
            for (int q = 0; q < 2; ++q) {
                sf[2*q]   = *(const f32x4*)&s_s[q*512 + lane*8];
                sf[2*q+1] = *(const f32x4*)&s_s[q*512 + lane*8 + 4];
            }
            for (int r = 0; r < 128; ++r) {
                const int d = w * 128 + r;
                const float* wr = W + (size_t)d * 1024;
                float sum = 0.f;
                #pragma unroll
                for (int q = 0; q < 2; ++q) {
                    f32x4 w0 = *(const f32x4*)(wr + q*512 + lane*8);
                    f32x4 w1 = *(const f32x4*)(wr + q*512 + lane*8 + 4);
                    #pragma unroll
                    for (int j = 0; j < 4; ++j) {
                        sum += w0[j] * sf[2*q][j];
                        sum += w1[j] * sf[2*q+1][j];
                    }
                }
                #pragma unroll
                for (int off = 32; off; off >>= 1) sum += __shfl_xor(sum, off, 64);
                if (lane == 0) chat_s[d] = sum;
            }
        }
        __syncthreads();
        {
            const int h0 = t * 2;
            float v0 = chat_s[h0], v1 = chat_s[h0+1];
            float ss = v0*v0 + v1*v1;
            #pragma unroll
            for (int off = 32; off; off >>= 1) ss += __shfl_xor(ss, off, 64);
            if (lane == 0) red_s[w] = ss;
            __syncthreads();
            float norm = 0.f;
            #pragma unroll
            for (int i = 0; i < 8; ++i) norm += red_s[i];
            const float scale = norm / ((1.f + norm) * sqrtf(norm) + 1e-30f);
            c_s[h0] = v0 * scale; c_s[h0+1] = v1 * scale;
        }
        __syncthreads();
        if (it < 2) {
            const int h0 = t * 2;
            float uu0 = 0.f, uu1 = 0.f;
            for (int d = 0; d < 1024; ++d) {
                f32x2 wv = *(const f32x2*)(W + (size_t)d * 1024 + h0);
                uu0 += c_s[d] * wv[0]; uu1 += c_s[d] * wv[1];
            }
            u_s[h0] = uu0; u_s[h0+1] = uu1;
        } else {
            const int h0 = t * 2;
            f32x2 ov; ov[0] = c_s[h0]; ov[1] = c_s[h0+1];
            *(f32x2*)(outp + (size_t)blockIdx.x * 1024 + h0) = ov;
        }
        __syncthreads();
    }
}

extern "C" void kernel_launch(void* const* d_in, const int* in_sizes, int n_in,
                              void* d_out, int out_size, void* d_ws, size_t ws_size,
                              hipStream_t stream)
{
    const float* enc = (const float*)d_in[0];   // [256,64,1024] fp32
    const float* W   = (const float*)d_in[1];   // [1024,1024]   fp32
    float* outp = (float*)d_out;                // [256,1024]    fp32
    (void)in_sizes; (void)n_in; (void)out_size;

    // ws layout (11.5 MB + barrier words)
    char* ws = (char*)d_ws;
    float*    b     = (float*)   (ws + 0x000000);  //  64 KB [256,64]
    __bf16*   s_hi  = (__bf16*)  (ws + 0x080000);  // 512 KB [256,1024]
    __bf16*   s_lo  = (__bf16*)  (ws + 0x100000);  // 512 KB
    float*    y0    = (float*)   (ws + 0x180000);  //   1 MB (y / chat lo-K)
    float*    y1    = (float*)   (ws + 0x280000);  //   1 MB (y / chat hi-K)
    __bf16*   Wx_hi = (__bf16*)  (ws + 0x380000);  //   2 MB  Wt then Wb
    __bf16*   Wx_lo = (__bf16*)  (ws + 0x580000);  //   2 MB
    __bf16*   Q_hi  = (__bf16*)  (ws + 0x780000);  //   2 MB [1024,1024]
    __bf16*   Q_lo  = (__bf16*)  (ws + 0x980000);  //   2 MB
    unsigned* bar   = (unsigned*)(ws + 0xB80000);  // 256 B barrier words

    if (ws_size < 0xB80100) {
        fallback_kernel<<<256, 512, 0, stream>>>(enc, W, outp);
        return;
    }

    // zero the barrier words (ws is poison-filled by the harness each run)
    hipMemsetAsync(bar, 0, 256, stream);

    fused_kernel<<<256, 1024, 0, stream>>>(
        enc, W, outp, b, s_hi, s_lo, y0, y1,
        Wx_hi, Wx_lo, Q_hi, Q_lo, bar);
}

// Round 9
// 188.312 us; speedup vs baseline: 2.4001x; 2.4001x over previous
//
#include <hip/hip_runtime.h>

// InductionNetwork capsule routing, C=256, K=64, H=1024, 3 iterations.
// R16: revert to R12's proven 8-dispatch structure (186us) after R15's
// flag-fused variant hung (dispatch order is undefined -> consumer blocks
// can occupy all CU slots before producers place -> deadlock; grid-wide
// rendezvous already measured ~40us/barrier in R13/R14 -> dead end).
// Two low-risk fixes on top of R12:
//  1. FAT register pin in routing: one asm pinning all 16 f32x4 at once
//     (per-element pins let the allocator remat; VGPR=64 observed R10-14)
//     + amdgpu_waves_per_eu(4,4) for the 128-VGPR budget. enc should now
//     be read ONCE per routing pass (was ~2x via L3 remat, ~29us -> ~15).
//  2. Q = W^T W is SYMMETRIC: compute 136 upper-triangle 64x64 tiles
//     (was 256), mirror-write off-diagonal tiles (packed bf16x4 stores).
// Dispatches (8):
//   A convwt||routing0   W -> Wt split-bf16 ; s = mean_k enc
//   B gemm_Q             Q = Wt Wt^T (136 triangular tiles + mirrors)
//   C gemm_y0||convWb    y = Q s (tiled) ; W -> Wb into Wx (Wt dead)
//   D routing1           norm=s.y -> scale; b = scale*(E.y); s
//   E gemm_y1            y = Q s (tiled)
//   F routing2           b += scale*(E.y); s
//   G gemm_chat          chat = W s (tiled, B = Wb)
//   H squash_out         out = squash(chat)
// Split-bf16 operands (verified R6-R14, absmax 4.88e-4):
//   D = Ah.Bh + Ah.Bl + Al.Bh with hi=bf16(x), lo=bf16(x-hi).
// Fragment layout verified R4/R6/R7: A[m=lane&15][k=(lane>>4)*8+j];
// C/D col=lane&15, row=(lane>>4)*4+reg.
// Fallback: R3's proven monolithic kernel if ws too small.

using f32x4  = __attribute__((ext_vector_type(4))) float;
using f32x2  = __attribute__((ext_vector_type(2))) float;
using bf16x8 = __attribute__((ext_vector_type(8))) __bf16;
using bf16x4 = __attribute__((ext_vector_type(4))) __bf16;

struct BfPair { __bf16 hi, lo; };
__device__ inline BfPair split_bf16(float x) {
    BfPair p;
    p.hi = (__bf16)x;
    p.lo = (__bf16)(x - (float)p.hi);
    return p;
}

// Fat pin: all 16 f32x4 live SIMULTANEOUSLY at this point. The per-element
// pin (R10-R14) let the allocator remat each value independently (VGPR=64
// observed throughout); this one cannot be satisfied without ~64 VGPRs of
// enc actually resident.
#define PIN_ER16(er) asm volatile("" : \
    "+v"(er[0][0]), "+v"(er[0][1]), "+v"(er[0][2]), "+v"(er[0][3]), \
    "+v"(er[1][0]), "+v"(er[1][1]), "+v"(er[1][2]), "+v"(er[1][3]), \
    "+v"(er[2][0]), "+v"(er[2][1]), "+v"(er[2][2]), "+v"(er[2][3]), \
    "+v"(er[3][0]), "+v"(er[3][1]), "+v"(er[3][2]), "+v"(er[3][3]))

// ---------------- shared LDS shapes ----------------------------------------
struct RoutSM {
    float spart[16][1024];  // 64 KB: per-wave partial s
    float u_s[1024];        //  4 KB: y staged for the dots
    float b_s[64], d_s[64], red_s[16], scale_s;
};

// ---------------- routing body (R11/R12 logic + fat pin) --------------------
// One block per capsule, 1024 threads = 16 waves. Wave w owns enc rows
// w*4..w*4+3; lane holds 16 floats/row (64 VGPRs, pinned).
// MODE 0: d uniform (iter 0). MODE 1: b = scale*(E.y). MODE 2: b += ...
template <int MODE>
__device__ __forceinline__ void routing_body(
    int c, const float* __restrict__ enc, const float* __restrict__ y0,
    const float* __restrict__ y1, float* __restrict__ bglob,
    __bf16* __restrict__ s_hi, __bf16* __restrict__ s_lo, RoutSM* sm)
{
    const int t = threadIdx.x, lane = t & 63, w = t >> 6;   // 16 waves
    const float* E = enc + (size_t)c * 65536;

    // small prologue loads first so their waitcnt doesn't drain er loads
    float yv = 0.f, sv = 0.f;
    if (MODE > 0) {
        const size_t o = (size_t)c * 1024 + t;
        yv = y0[o] + y1[o];                       // y = Q s (full K)
        sv = (float)s_hi[o] + (float)s_lo[o];     // s as the gemm saw it
    }

    f32x4 er[4][4];                     // 64 VGPRs of enc
    #pragma unroll
    for (int r = 0; r < 4; ++r) {
        const float* ek = E + (size_t)(w * 4 + r) * 1024 + lane * 8;
        er[r][0] = *(const f32x4*)(ek);
        er[r][1] = *(const f32x4*)(ek + 4);
        er[r][2] = *(const f32x4*)(ek + 512);
        er[r][3] = *(const f32x4*)(ek + 516);
    }
    PIN_ER16(er);

    if (MODE > 0) {
        sm->u_s[t] = yv;
        float p = yv * sv;                        // norm = s^T Q s = |W s|^2
        #pragma unroll
        for (int off = 32; off; off >>= 1) p += __shfl_xor(p, off, 64);
        if (lane == 0) sm->red_s[w] = p;
        __syncthreads();
        if (t == 0) {
            float n = 0.f;
            #pragma unroll
            for (int i = 0; i < 16; ++i) n += sm->red_s[i];
            sm->scale_s = n / ((1.f + n) * sqrtf(n) + 1e-30f);
        }
        __syncthreads();
        const float scale = sm->scale_s;
        f32x4 uf[4];
        uf[0] = *(const f32x4*)&sm->u_s[lane * 8];
        uf[1] = *(const f32x4*)&sm->u_s[lane * 8 + 4];
        uf[2] = *(const f32x4*)&sm->u_s[512 + lane * 8];
        uf[3] = *(const f32x4*)&sm->u_s[512 + lane * 8 + 4];
        #pragma unroll
        for (int r = 0; r < 4; ++r) {
            float sum = 0.f;
            #pragma unroll
            for (int q = 0; q < 4; ++q)
                #pragma unroll
                for (int j = 0; j < 4; ++j)
                    sum += er[r][q][j] * uf[q][j];
            #pragma unroll
            for (int off = 32; off; off >>= 1) sum += __shfl_xor(sum, off, 64);
            if (lane == 0) {
                const int k = w * 4 + r;
                const float bv =
                    (MODE == 2 ? bglob[c * 64 + k] : 0.f) + scale * sum;
                bglob[c * 64 + k] = bv;     // persist for next iteration
                sm->b_s[k] = bv;
            }
        }
    }
    __syncthreads();

    if (MODE == 0) {
        if (t < 64) sm->d_s[t] = 1.f / 64.f;
    } else if (t < 64) {
        float bv = sm->b_s[t], m = bv;
        #pragma unroll
        for (int off = 32; off; off >>= 1) m = fmaxf(m, __shfl_xor(m, off, 64));
        const float e = expf(bv - m);
        float smm = e;
        #pragma unroll
        for (int off = 32; off; off >>= 1) smm += __shfl_xor(smm, off, 64);
        sm->d_s[t] = e / smm;
    }
    __syncthreads();

    PIN_ER16(er);   // er must still be live here: no remat/reload possible

    // per-wave partial s from registers (4 rows each)
    #pragma unroll
    for (int q = 0; q < 4; ++q) {
        f32x4 p = {};
        #pragma unroll
        for (int r = 0; r < 4; ++r) {
            const float dk = sm->d_s[w * 4 + r];
            #pragma unroll
            for (int j = 0; j < 4; ++j) p[j] += dk * er[r][q][j];
        }
        const int h = (q >> 1) * 512 + lane * 8 + (q & 1) * 4;
        *(f32x4*)&sm->spart[w][h] = p;
    }
    __syncthreads();

    // cross-wave reduce: 1 h-element per thread; emit split-bf16 s
    {
        float a = 0.f;
        #pragma unroll
        for (int wv = 0; wv < 16; ++wv) a += sm->spart[wv][t];
        const BfPair p = split_bf16(a);
        s_hi[(size_t)c * 1024 + t] = p.hi;
        s_lo[(size_t)c * 1024 + t] = p.lo;
    }
}

// Routing dispatch. WITH_CONV: blocks [0,256) do W -> Wt split-bf16
// (transposed, 64x64 LDS tiles); routing capsules are blocks [256,512).
template <int MODE, int WITH_CONV>
__global__ __launch_bounds__(1024, 4)
__attribute__((amdgpu_waves_per_eu(4, 4)))
void routing_kernel(
    const float* __restrict__ enc, const float* __restrict__ y0,
    const float* __restrict__ y1, float* __restrict__ bglob,
    __bf16* __restrict__ s_hi, __bf16* __restrict__ s_lo,
    const float* __restrict__ W, __bf16* __restrict__ Wt_hi,
    __bf16* __restrict__ Wt_lo)
{
    __shared__ union {
        RoutSM r;
        float tile[64][65];     // 16.6 KB: conv transpose staging
    } sm;

    int c = blockIdx.x;
    if (WITH_CONV) {
        if (blockIdx.x < 256) {
            const int by = blockIdx.x >> 4, bx = blockIdx.x & 15;
            const int tx = threadIdx.x & 63, ty = threadIdx.x >> 6;
            for (int i = ty; i < 64; i += 16)
                sm.tile[i][tx] = W[(size_t)(by * 64 + i) * 1024 + bx * 64 + tx];
            __syncthreads();
            for (int i = ty; i < 64; i += 16) {
                const size_t idx = (size_t)(bx * 64 + i) * 1024 + by * 64 + tx;
                const BfPair p = split_bf16(sm.tile[tx][i]);
                Wt_hi[idx] = p.hi;
                Wt_lo[idx] = p.lo;
            }
            return;
        }
        c = blockIdx.x - 256;
    }
    routing_body<MODE>(c, enc, y0, y1, bglob, s_hi, s_lo, &sm.r);
}

// ---------------- LDS-tiled GEMM machinery ---------------------------------
struct QSmem {
    __bf16 a_hi[64 * 64];
    __bf16 a_lo[64 * 64];
    __bf16 b_hi[64 * 64];
    __bf16 b_lo[64 * 64];
};

__device__ __forceinline__ int swz128(int row, int colbyte) {
    // 128-byte rows; XOR bits 4-6 of the byte offset with row&7
    return row * 128 + (colbyte ^ ((row & 7) << 4));
}

// ---- Q = Wt Wt^T (= W^T W): SYMMETRIC -> 136 upper-triangle tiles
// (ti <= tj), mirror-write off-diagonal tiles. 256 threads = 4 waves in a
// 2x2 grid, each wave a 32x32 sub-tile (2x2 16x16 frags), BK=64 LDS
// staging, XOR-swizzled rows. Writes split-bf16 Q. (body verified R11/R12)
__global__ __launch_bounds__(256) void gemm_q_kernel(
    const __bf16* __restrict__ Wt_hi, const __bf16* __restrict__ Wt_lo,
    __bf16* __restrict__ Q_hi, __bf16* __restrict__ Q_lo)
{
    __shared__ QSmem sm;
    // triangular index: tile (ti, tj) with ti <= tj, b = T(tj) + ti
    const int b = blockIdx.x;
    int tj = (int)((sqrtf(8.f * (float)b + 1.f) - 1.f) * 0.5f);
    while ((tj + 1) * (tj + 2) / 2 <= b) ++tj;
    while (tj * (tj + 1) / 2 > b) --tj;
    const int ti = b - tj * (tj + 1) / 2;

    const int t = threadIdx.x;
    const int lane = t & 63, w = t >> 6;        // 4 waves
    const int wr = w >> 1, wc = w & 1;          // wave's 32x32 sub-tile
    const int sr  = t >> 2;                     // row 0..63
    const int scb = (t & 3) * 16;               // col byte {0,16,32,48}
    const size_t ga = (size_t)(ti * 64 + sr) * 1024 + scb / 2;
    const size_t gb = (size_t)(tj * 64 + sr) * 1024 + scb / 2;

    f32x4 acc[2][2] = {};
    for (int k0 = 0; k0 < 1024; k0 += 64) {
        if (k0) __syncthreads();                // prev step's reads done
        #pragma unroll
        for (int h = 0; h < 2; ++h) {
            const int cb = scb + h * 64;        // covers full 128-B row
            const size_t gao = ga + h * 32 + k0;
            const size_t gbo = gb + h * 32 + k0;
            *(bf16x8*)((char*)sm.a_hi + swz128(sr, cb)) = *(const bf16x8*)(Wt_hi + gao);
            *(bf16x8*)((char*)sm.a_lo + swz128(sr, cb)) = *(const bf16x8*)(Wt_lo + gao);
            *(bf16x8*)((char*)sm.b_hi + swz128(sr, cb)) = *(const bf16x8*)(Wt_hi + gbo);
            *(bf16x8*)((char*)sm.b_lo + swz128(sr, cb)) = *(const bf16x8*)(Wt_lo + gbo);
        }
        __syncthreads();
        #pragma unroll
        for (int kk = 0; kk < 2; ++kk) {
            const int cb = kk * 64 + (lane >> 4) * 16;  // col byte of frag
            bf16x8 ah[2], al[2], bh[2], bl[2];
            #pragma unroll
            for (int mi = 0; mi < 2; ++mi) {
                const int m = wr * 32 + mi * 16 + (lane & 15);
                ah[mi] = *(const bf16x8*)((char*)sm.a_hi + swz128(m, cb));
                al[mi] = *(const bf16x8*)((char*)sm.a_lo + swz128(m, cb));
            }
            #pragma unroll
            for (int ni = 0; ni < 2; ++ni) {
                const int n = wc * 32 + ni * 16 + (lane & 15);
                bh[ni] = *(const bf16x8*)((char*)sm.b_hi + swz128(n, cb));
                bl[ni] = *(const bf16x8*)((char*)sm.b_lo + swz128(n, cb));
            }
            #pragma unroll
            for (int mi = 0; mi < 2; ++mi)
                #pragma unroll
                for (int ni = 0; ni < 2; ++ni) {
                    f32x4 a = acc[mi][ni];
                    a = __builtin_amdgcn_mfma_f32_16x16x32_bf16(ah[mi], bh[ni], a, 0, 0, 0);
                    a = __builtin_amdgcn_mfma_f32_16x16x32_bf16(ah[mi], bl[ni], a, 0, 0, 0);
                    a = __builtin_amdgcn_mfma_f32_16x16x32_bf16(al[mi], bh[ni], a, 0, 0, 0);
                    acc[mi][ni] = a;
                }
        }
    }
    const int rr = (lane >> 4) * 4, colb = lane & 15;
    #pragma unroll
    for (int mi = 0; mi < 2; ++mi)
        #pragma unroll
        for (int ni = 0; ni < 2; ++ni) {
            bf16x4 hv, lv;
            #pragma unroll
            for (int r = 0; r < 4; ++r) {
                const BfPair p = split_bf16(acc[mi][ni][r]);
                const size_t idx =
                    (size_t)(ti * 64 + wr * 32 + mi * 16 + rr + r) * 1024 +
                    tj * 64 + wc * 32 + ni * 16 + colb;
                Q_hi[idx] = p.hi;
                Q_lo[idx] = p.lo;
                hv[r] = p.hi;
                lv[r] = p.lo;
            }
            if (ti != tj) {
                // mirror: Q[col][row..row+3] = same 4 values, packed 8B
                const size_t midx =
                    (size_t)(tj * 64 + wc * 32 + ni * 16 + colb) * 1024 +
                    ti * 64 + wr * 32 + mi * 16 + rr;
                *(bf16x4*)(Q_hi + midx) = hv;
                *(bf16x4*)(Q_lo + midx) = lv;
            }
        }
}

// ---- tiled split-bf16 NT GEMM, split-K x2: C[256,1024] = A[256,:] B^T.
// 128 blocks: kh = bx&1, task = bx>>1 -> mt (4 x 64 rows), nt (16 x 64
// cols). 256 thr = 4 waves (2x2 of 32x32). BK=64 LDS staging, swizzled.
// With CONV, blocks [128,384) convert W fp32 -> split-bf16 Wd (coalesced).
template <int CONV>
__global__ __launch_bounds__(256) void gemm_nt_kernel(
    const __bf16* __restrict__ Ah, const __bf16* __restrict__ Al,
    const __bf16* __restrict__ Bh, const __bf16* __restrict__ Bl,
    float* __restrict__ C0, float* __restrict__ C1,
    const float* __restrict__ Wsrc, __bf16* __restrict__ Wd_hi,
    __bf16* __restrict__ Wd_lo)
{
    __shared__ QSmem sm;
    if (CONV && blockIdx.x >= 128) {
        const int b = blockIdx.x - 128;             // 0..255
        const size_t base = (size_t)b * 4096 + (threadIdx.x << 2);
        #pragma unroll
        for (int q = 0; q < 4; ++q) {
            const size_t idx = base + (size_t)q * 1024;
            const f32x4 v = *(const f32x4*)(Wsrc + idx);
            bf16x4 hv, lv;
            #pragma unroll
            for (int j = 0; j < 4; ++j) {
                const BfPair p = split_bf16(v[j]);
                hv[j] = p.hi;
                lv[j] = p.lo;
            }
            *(bf16x4*)(Wd_hi + idx) = hv;
            *(bf16x4*)(Wd_lo + idx) = lv;
        }
        return;
    }

    const int kh   = blockIdx.x & 1;
    const int task = blockIdx.x >> 1;
    const int mt   = task >> 4;                 // 0..3   (64-row panel)
    const int nt   = task & 15;                 // 0..15  (64-col panel)
    const int t = threadIdx.x;
    const int lane = t & 63, w = t >> 6;        // 4 waves
    const int wr = w >> 1, wc = w & 1;          // wave's 32x32 sub-tile
    const int sr  = t >> 2;                     // row 0..63
    const int scb = (t & 3) * 16;               // col byte {0,16,32,48}
    const size_t ga = (size_t)(mt * 64 + sr) * 1024 + kh * 512 + scb / 2;
    const size_t gb = (size_t)(nt * 64 + sr) * 1024 + kh * 512 + scb / 2;

    f32x4 acc[2][2] = {};
    for (int k0 = 0; k0 < 512; k0 += 64) {
        if (k0) __syncthreads();                // prev step's reads done
        #pragma unroll
        for (int h = 0; h < 2; ++h) {
            const int cb = scb + h * 64;        // covers full 128-B row
            const size_t gao = ga + h * 32 + k0;
            const size_t gbo = gb + h * 32 + k0;
            *(bf16x8*)((char*)sm.a_hi + swz128(sr, cb)) = *(const bf16x8*)(Ah + gao);
            *(bf16x8*)((char*)sm.a_lo + swz128(sr, cb)) = *(const bf16x8*)(Al + gao);
            *(bf16x8*)((char*)sm.b_hi + swz128(sr, cb)) = *(const bf16x8*)(Bh + gbo);
            *(bf16x8*)((char*)sm.b_lo + swz128(sr, cb)) = *(const bf16x8*)(Bl + gbo);
        }
        __syncthreads();
        #pragma unroll
        for (int kk = 0; kk < 2; ++kk) {
            const int cb = kk * 64 + (lane >> 4) * 16;  // col byte of frag
            bf16x8 ah[2], al[2], bh[2], bl[2];
            #pragma unroll
            for (int mi = 0; mi < 2; ++mi) {
                const int m = wr * 32 + mi * 16 + (lane & 15);
                ah[mi] = *(const bf16x8*)((char*)sm.a_hi + swz128(m, cb));
                al[mi] = *(const bf16x8*)((char*)sm.a_lo + swz128(m, cb));
            }
            #pragma unroll
            for (int ni = 0; ni < 2; ++ni) {
                const int n = wc * 32 + ni * 16 + (lane & 15);
                bh[ni] = *(const bf16x8*)((char*)sm.b_hi + swz128(n, cb));
                bl[ni] = *(const bf16x8*)((char*)sm.b_lo + swz128(n, cb));
            }
            #pragma unroll
            for (int mi = 0; mi < 2; ++mi)
                #pragma unroll
                for (int ni = 0; ni < 2; ++ni) {
                    f32x4 a = acc[mi][ni];
                    a = __builtin_amdgcn_mfma_f32_16x16x32_bf16(ah[mi], bh[ni], a, 0, 0, 0);
                    a = __builtin_amdgcn_mfma_f32_16x16x32_bf16(ah[mi], bl[ni], a, 0, 0, 0);
                    a = __builtin_amdgcn_mfma_f32_16x16x32_bf16(al[mi], bh[ni], a, 0, 0, 0);
                    acc[mi][ni] = a;
                }
        }
    }
    float* Cc = kh ? C1 : C0;
    const int rr = (lane >> 4) * 4, colb = lane & 15;
    #pragma unroll
    for (int mi = 0; mi < 2; ++mi)
        #pragma unroll
        for (int ni = 0; ni < 2; ++ni)
            #pragma unroll
            for (int r = 0; r < 4; ++r)
                Cc[(size_t)(mt * 64 + wr * 32 + mi * 16 + rr + r) * 1024 +
                   nt * 64 + wc * 32 + ni * 16 + colb] = acc[mi][ni][r];
}

// ---------------- final squash: sums split-K chat, emits out ---------------
__global__ __launch_bounds__(256) void squash_out_kernel(
    const float* __restrict__ chat0, const float* __restrict__ chat1,
    float* __restrict__ outp)
{
    __shared__ float wsum[4];
    const int c = blockIdx.x, t = threadIdx.x;
    const int lane = t & 63, w = t >> 6;
    const size_t o = (size_t)c * 1024 + t * 4;
    f32x4 v = *(const f32x4*)(chat0 + o) + *(const f32x4*)(chat1 + o);
    float ss = v[0]*v[0] + v[1]*v[1] + v[2]*v[2] + v[3]*v[3];
    #pragma unroll
    for (int off = 32; off; off >>= 1) ss += __shfl_xor(ss, off, 64);
    if (lane == 0) wsum[w] = ss;
    __syncthreads();
    const float norm = wsum[0] + wsum[1] + wsum[2] + wsum[3];
    const float scale = norm / ((1.f + norm) * sqrtf(norm) + 1e-30f);
    *(f32x4*)(outp + o) = v * scale;
}

// ---------------- fallback: R3's proven monolithic fp32 kernel --------------
__global__ __launch_bounds__(512) void fallback_kernel(
    const float* __restrict__ enc, const float* __restrict__ W,
    float* __restrict__ outp)
{
    __shared__ float u_s[1024], s_s[1024], c_s[1024], chat_s[1024];
    __shared__ float b_s[64], d_s[64], red_s[8];
    const int t = threadIdx.x, lane = t & 63, w = t >> 6;
    const float* erow = enc + (size_t)blockIdx.x * 65536;

    if (t < 64) b_s[t] = 0.f;
    __syncthreads();

    for (int it = 0; it < 3; ++it) {
        if (it > 0) {
            f32x4 uf[4];
            #pragma unroll
            for (int q = 0; q < 2; ++q) {
                uf[2*q]   = *(const f32x4*)&u_s[q*512 + lane*8];
                uf[2*q+1] = *(const f32x4*)&u_s[q*512 + lane*8 + 4];
            }
            for (int r = 0; r < 8; ++r) {
                const int k = w * 8 + r;
                const float* ek = erow + (size_t)k * 1024;
                float sum = 0.f;
                #pragma unroll
                for (int q = 0; q < 2; ++q) {
                    f32x4 e0 = *(const f32x4*)(ek + q*512 + lane*8);
                    f32x4 e1 = *(const f32x4*)(ek + q*512 + lane*8 + 4);
                    #pragma unroll
                    for (int j = 0; j < 4; ++j) {
                        sum += e0[j] * uf[2*q][j];
                        sum += e1[j] * uf[2*q+1][j];
                    }
                }
                #pragma unroll
                for (int off = 32; off; off >>= 1) sum += __shfl_xor(sum, off, 64);
                if (lane == 0) b_s[k] += sum;
            }
            __syncthreads();
        }
        if (t < 64) {
            float bv = b_s[t], m = bv;
            #pragma unroll
            for (int off = 32; off; off >>= 1) m = fmaxf(m, __shfl_xor(m, off, 64));
            float e = expf(bv - m), sm = e;
            #pragma unroll
            for (int off = 32; off; off >>= 1) sm += __shfl_xor(sm, off, 64);
            d_s[t] = e / sm;
        }
        __syncthreads();
        {
            const int h0 = t * 2;
            float a0 = 0.f, a1 = 0.f;
            for (int k = 0; k < 64; ++k) {
                f32x2 ev = *(const f32x2*)(erow + (size_t)k * 1024 + h0);
                a0 += d_s[k] * ev[0]; a1 += d_s[k] * ev[1];
            }
            s_s[h0] = a0; s_s[h0+1] = a1;
        }
        __syncthreads();
        {
            f32x4 sf[4];
            #pragma unroll
            for (int q = 0; q < 2; ++q) {
                sf[2*q]   = *(const f32x4*)&s_s[q*512 + lane*8];
                sf[2*q+1] = *(const f32x4*)&s_s[q*512 + lane*8 + 4];
            }
            for (int r = 0; r < 128; ++r) {
                const int d = w * 128 + r;
                const float* wr = W + (size_t)d * 1024;
                float sum = 0.f;
                #pragma unroll
                for (int q = 0; q < 2; ++q) {
                    f32x4 w0 = *(const f32x4*)(wr + q*512 + lane*8);
                    f32x4 w1 = *(const f32x4*)(wr + q*512 + lane*8 + 4);
                    #pragma unroll
                    for (int j = 0; j < 4; ++j) {
                        sum += w0[j] * sf[2*q][j];
                        sum += w1[j] * sf[2*q+1][j];
                    }
                }
                #pragma unroll
                for (int off = 32; off; off >>= 1) sum += __shfl_xor(sum, off, 64);
                if (lane == 0) chat_s[d] = sum;
            }
        }
        __syncthreads();
        {
            const int h0 = t * 2;
            float v0 = chat_s[h0], v1 = chat_s[h0+1];
            float ss = v0*v0 + v1*v1;
            #pragma unroll
            for (int off = 32; off; off >>= 1) ss += __shfl_xor(ss, off, 64);
            if (lane == 0) red_s[w] = ss;
            __syncthreads();
            float norm = 0.f;
            #pragma unroll
            for (int i = 0; i < 8; ++i) norm += red_s[i];
            const float scale = norm / ((1.f + norm) * sqrtf(norm) + 1e-30f);
            c_s[h0] = v0 * scale; c_s[h0+1] = v1 * scale;
        }
        __syncthreads();
        if (it < 2) {
            const int h0 = t * 2;
            float uu0 = 0.f, uu1 = 0.f;
            for (int d = 0; d < 1024; ++d) {
                f32x2 wv = *(const f32x2*)(W + (size_t)d * 1024 + h0);
                uu0 += c_s[d] * wv[0]; uu1 += c_s[d] * wv[1];
            }
            u_s[h0] = uu0; u_s[h0+1] = uu1;
        } else {
            const int h0 = t * 2;
            f32x2 ov; ov[0] = c_s[h0]; ov[1] = c_s[h0+1];
            *(f32x2*)(outp + (size_t)blockIdx.x * 1024 + h0) = ov;
        }
        __syncthreads();
    }
}

extern "C" void kernel_launch(void* const* d_in, const int* in_sizes, int n_in,
                              void* d_out, int out_size, void* d_ws, size_t ws_size,
                              hipStream_t stream)
{
    const float* enc = (const float*)d_in[0];   // [256,64,1024] fp32
    const float* W   = (const float*)d_in[1];   // [1024,1024]   fp32
    float* outp = (float*)d_out;                // [256,1024]    fp32
    (void)in_sizes; (void)n_in; (void)out_size;

    // ws layout (11.5 MB)
    char* ws = (char*)d_ws;
    float*  b     = (float*) (ws + 0x000000);  //  64 KB [256,64]
    __bf16* s_hi  = (__bf16*)(ws + 0x080000);  // 512 KB [256,1024]
    __bf16* s_lo  = (__bf16*)(ws + 0x100000);  // 512 KB
    float*  y0    = (float*) (ws + 0x180000);  //   1 MB (y / chat, split-K lo)
    float*  y1    = (float*) (ws + 0x280000);  //   1 MB (y / chat, split-K hi)
    __bf16* Wx_hi = (__bf16*)(ws + 0x380000);  //   2 MB  Wt then Wb (reuse)
    __bf16* Wx_lo = (__bf16*)(ws + 0x580000);  //   2 MB
    __bf16* Q_hi  = (__bf16*)(ws + 0x780000);  //   2 MB [1024,1024]
    __bf16* Q_lo  = (__bf16*)(ws + 0x980000);  //   2 MB

    if (ws_size < 0xB80000) {
        fallback_kernel<<<256, 512, 0, stream>>>(enc, W, outp);
        return;
    }

    // A: convert_wt (blocks 0..255) || routing iter0 (blocks 256..511)
    routing_kernel<0, 1><<<512, 1024, 0, stream>>>(
        enc, y0, y1, b, s_hi, s_lo, W, Wx_hi, Wx_lo);

    // B: Q = Wt Wt^T (136 triangular tiles, mirror-written)
    gemm_q_kernel<<<136, 256, 0, stream>>>(Wx_hi, Wx_lo, Q_hi, Q_lo);

    // C: y = Q s (tiled)  || convert W -> Wb into the (now dead) Wt buffer
    gemm_nt_kernel<1><<<384, 256, 0, stream>>>(
        s_hi, s_lo, Q_hi, Q_lo, y0, y1, W, Wx_hi, Wx_lo);

    // D: routing iter1 (norm = s.y -> scale; b = scale*(E.y); new s)
    routing_kernel<1, 0><<<256, 1024, 0, stream>>>(
        enc, y0, y1, b, s_hi, s_lo, nullptr, nullptr, nullptr);

    // E: y = Q s (tiled)
    gemm_nt_kernel<0><<<128, 256, 0, stream>>>(
        s_hi, s_lo, Q_hi, Q_lo, y0, y1, nullptr, nullptr, nullptr);

    // F: routing iter2 (b += scale*(E.y); final s)
    routing_kernel<2, 0><<<256, 1024, 0, stream>>>(
        enc, y0, y1, b, s_hi, s_lo, nullptr, nullptr, nullptr);

    // G: chat = W s (tiled, B = Wb in Wx)
    gemm_nt_kernel<0><<<128, 256, 0, stream>>>(
        s_hi, s_lo, Wx_hi, Wx_lo, y0, y1, nullptr, nullptr, nullptr);

    // H: out = squash(chat)
    squash_out_kernel<<<256, 256, 0, stream>>>(y0, y1, outp);
}